// Round 6
// baseline (695.867 us; speedup 1.0000x reference)
//
#include <hip/hip_runtime.h>

#define NN 2048
#define NE 32768
#define DF 2048
#define TOPK 20
#define RMAXF 1e-5f
#define MAXD 48           // supported max in-degree (Poisson(16); verified by passing rounds)
#define MAXDQ (MAXD / 4)  // 12 quad-levels of 4 packed edges
#define SENTW 0x80008000u // two packed PRE-SCALED sentinel ids (2048<<4 -> PV sentinel slot)
#define NSRC 4            // sources per block (float4-packed PV)
#define MAXROUNDS 64      // safety cap; provably unreachable (mass halves/round)
#define NL 4              // owned nodes per thread (512 threads)

typedef __attribute__((ext_vector_type(4))) float f32x4;

// ---------------- init: zero counters, sentinel-fill transposed in-edge table ----------------
__global__ __launch_bounds__(256) void init_kernel(int* __restrict__ outcnt, int* __restrict__ incur,
                                                   unsigned* __restrict__ T) {
    int i = blockIdx.x * 256 + threadIdx.x;
    if (i < MAXDQ * NN * 2) T[i] = SENTW;
    if (i < NN) { outcnt[i] = 0; incur[i] = 0; }
}

// ---------------- build: out-degree counts + transposed (CSC) quad-packed fill ----------------
// Halfwords hold PRE-SCALED ids (s<<4 = byte offset of node s in the f32x4 PV array; max
// 0x8000 fits u16). Level-major: quad-level q of node j at uint2 index q*NN + j. Slot p of
// node d: word = (p>>2)*(NN*2) + d*2 + ((p>>1)&1), halfword = p&1. And+Or race only with
// the other half of the same word (disjoint masks) -> safe.
__global__ __launch_bounds__(256) void build_kernel(const int* __restrict__ ei, int* __restrict__ outcnt,
                                                    int* __restrict__ incur, unsigned* __restrict__ T) {
    int e = blockIdx.x * 256 + threadIdx.x;
    if (e >= NE) return;
    int s = ei[e];
    int d = ei[NE + e];
    atomicAdd(&outcnt[s], 1);
    int p = atomicAdd(&incur[d], 1);
    if (p < MAXD) {
        int wi = (p >> 2) * (NN * 2) + d * 2 + ((p >> 1) & 1);
        int sh = (p & 1) * 16;
        atomicAnd(&T[wi], ~(0xFFFFu << sh));
        atomicOr(&T[wi], ((unsigned)(s << 4)) << sh);
    }
}

// ---------------- winv05 = 0.5/outdeg; per-64-node-group quad-level bound ----------------
__global__ __launch_bounds__(256) void meta_kernel(const int* __restrict__ outcnt, const int* __restrict__ incur,
                                                   float* __restrict__ winv05, int* __restrict__ gmaxq) {
    int tid = threadIdx.x;
#pragma unroll
    for (int l = 0; l < 8; ++l) {
        int j = tid + (l << 8);
        int c = outcnt[j];
        winv05[j] = c ? 0.5f / (float)c : 0.0f;  // deg==0 row spreads nothing
    }
    if (tid < 32) {
        int m = 0;
        for (int k = 0; k < 64; ++k) m = max(m, incur[tid * 64 + k]);
        m = min(m, MAXD);
        gmaxq[tid] = (m + 3) >> 2;
    }
}

// ---------------- one synchronous push round, parity-specialized ----------------
// P = read-buffer parity. Compile-time LDS read base folds into the ds_read offset
// immediate; pre-scaled halfwords are direct byte offsets -> per edge: 1 extract +
// 1 ds_read_b128 + 2 v_pk_add. Dual accumulators halve the serial add chain.
template <int P>
__device__ __forceinline__ bool round_step(const uint2* __restrict__ Tq, f32x4* PVbuf,
                                           unsigned (&swfw)[2][4], f32x4 (&Rr)[NL], f32x4 (&Pr)[NL],
                                           const float (&wvv)[NL], const int (&gql)[NL],
                                           int tid, int lane, int wvid) {
    const char* pvr = (const char*)PVbuf + P * ((NN + 1) * 16);
    f32x4* PVn = PVbuf + (P ^ 1) * (NN + 1);
    const f32x4 z = {0.f, 0.f, 0.f, 0.f};
    bool above = false;
#pragma unroll
    for (int l = 0; l < NL; ++l) {
        int j = tid + (l << 9);
        const uint2* colq = Tq + j;
        int gq = gql[l];
        f32x4 d0 = z, d1 = z;
#pragma unroll 4
        for (int q = 0; q < gq; ++q) {
            uint2 w = colq[q * NN];  // coalesced 512B/wave, L2-resident
            d0 += *(const f32x4*)(pvr + (w.x & 0xFFFFu));
            d1 += *(const f32x4*)(pvr + (w.x >> 16));
            d0 += *(const f32x4*)(pvr + (w.y & 0xFFFFu));
            d1 += *(const f32x4*)(pvr + (w.y >> 16));
        }
        f32x4 rn = Rr[l] + (d0 + d1);
        f32x4 pv;
#pragma unroll
        for (int u = 0; u < 4; ++u) {
            float r = rn[u];
            if (r >= RMAXF) {
                Pr[l][u] += 0.5f * r;
                pv[u] = r * wvv[l];
                rn[u] = 0.0f;
                above = true;
            } else {
                pv[u] = 0.0f;
            }
        }
        PVn[j] = pv;
        Rr[l] = rn;
    }
    int anyv = __any(above) ? 1 : 0;  // all lanes participate
    if (lane == 0) ((unsigned char*)&swfw[P][0])[wvid] = (unsigned char)anyv;  // distinct bytes
    __syncthreads();  // PVn writes + flag bytes visible; pvr reads done
    uint4 f = *(const uint4*)&swfw[P][0];  // 16 wave flags in one ds_read_b128
    return (f.x | f.y | f.z | f.w) != 0u;
}

// ---------------- 4-source local push (gather form, ping-pong PV) + per-wave top-20 ----------------
// 512 threads x 4 owned nodes (state sized to the proven no-spill footprint; rounds 3/4
// showed 8 nodes of f32x4 state spills to scratch). PV float4-packed: component c = source
// 4*blockIdx+c; one ds_read_b128 per edge-id serves 4 sources. One barrier per round.
// Convergence flags: per-wave bytes written unconditionally each round, parity-alternated.
__global__ __launch_bounds__(512, 2) void push_topk_kernel(const unsigned* __restrict__ Tw,
                                                           const float* __restrict__ winv05g,
                                                           const int* __restrict__ gmaxqg,
                                                           float* __restrict__ tkv, int* __restrict__ tki) {
    __shared__ f32x4 PVbuf[2 * (NN + 1)];           // [parity][node]; [*][NN] = zero sentinel
    __shared__ __align__(16) unsigned swfw[2][4];   // [parity][16 wave flag bytes]

    const int tid = threadIdx.x;
    const int lane = tid & 63;
    const int wvid = tid >> 6;  // 0..7
    const int s0 = blockIdx.x * NSRC;
    const uint2* Tq = (const uint2*)Tw;
    const f32x4 z = {0.f, 0.f, 0.f, 0.f};

    f32x4 Rr[NL], Pr[NL];
    float wvv[NL];
    int gql[NL];  // wave-uniform in-degree bounds -> SGPRs (group of j=tid+l*512 is wvid+8l)
#pragma unroll
    for (int l = 0; l < NL; ++l) gql[l] = __builtin_amdgcn_readfirstlane(gmaxqg[wvid + (l << 3)]);

#pragma unroll
    for (int l = 0; l < NL; ++l) {
        int j = tid + (l << 9);
        Rr[l] = z;
        Pr[l] = z;
        wvv[l] = winv05g[j];
        PVbuf[j] = z;  // buffer 0; buffer 1 fully written in round 0 before round 1 reads it
    }
    if (tid == 0) { PVbuf[NN] = z; PVbuf[2 * NN + 1] = z; }  // both sentinels, never rewritten
    // fold reference round 1 (only the source is >= RMAX): P[s][c]=0.5, PV0[s][c]=winv05[s]
#pragma unroll
    for (int l = 0; l < NL; ++l) {
        int j = tid + (l << 9);
#pragma unroll
        for (int c = 0; c < NSRC; ++c) {
            if (j == s0 + c) {
                Pr[l][c] = 0.5f;
                ((float*)&PVbuf[j])[c] = wvv[l];  // compile-time c -> single ds_write_b32
            }
        }
    }
    __syncthreads();

    int flagreg = 1;
    for (int round = 0; flagreg && round < MAXROUNDS; round += 2) {
        flagreg = round_step<0>(Tq, PVbuf, swfw, Rr, Pr, wvv, gql, tid, lane, wvid);
        if (!flagreg) break;
        flagreg = round_step<1>(Tq, PVbuf, swfw, Rr, Pr, wvv, gql, tid, lane, wvid);
    }

    // ---- top-20: dump P into dead PV (buffer 0); waves 0..3 each extract one source ----
#pragma unroll
    for (int l = 0; l < NL; ++l) PVbuf[tid + (l << 9)] = Pr[l];
    __syncthreads();

    const int w = wvid;  // wave id == source component
    if (w < NSRC) {
        float* Psh = (float*)PVbuf;  // value of node n, source w at Psh[(n<<2) + w]
        float bv = -2.0f;
        int bi = 0;
#pragma unroll
        for (int k = 0; k < 32; ++k) {  // k ascending => node ascending; strict > keeps lowest
            int n = lane + (k << 6);
            float v = Psh[(n << 2) + w];
            if (v > bv) { bv = v; bi = n; }
        }
        for (int s = 0; s < TOPK; ++s) {
            float mv = bv;
            int mi = bi;
#pragma unroll
            for (int off = 32; off > 0; off >>= 1) {  // butterfly argmax, lowest index on ties
                float ov = __shfl_xor(mv, off, 64);
                int oi = __shfl_xor(mi, off, 64);
                if (ov > mv || (ov == mv && oi < mi)) { mv = ov; mi = oi; }
            }
            if (lane == 0) {
                tkv[(s0 + w) * TOPK + s] = mv;
                tki[(s0 + w) * TOPK + s] = mi;
            }
            if ((mi & 63) == lane) {  // owner pops winner, rescans its 32 (static indexing only)
                Psh[(mi << 2) + w] = -1.0f;  // P >= 0, safe sentinel
                bv = -2.0f;
                bi = 0;
#pragma unroll
                for (int k = 0; k < 32; ++k) {
                    int n = lane + (k << 6);
                    float v = Psh[(n << 2) + w];
                    if (v > bv) { bv = v; bi = n; }
                }
            }
        }
    }
}

// ---------------- out[row] = sum_v w_v * feats[idx_v] ----------------
__global__ __launch_bounds__(256) void final_kernel(const float* __restrict__ feats, const float* __restrict__ tkv,
                                                    const int* __restrict__ tki, float* __restrict__ out) {
    __shared__ float wvs[TOPK];
    __shared__ int wis[TOPK];
    int row = blockIdx.x, tid = threadIdx.x;
    if (tid < TOPK) {
        wvs[tid] = tkv[row * TOPK + tid];
        wis[tid] = tki[row * TOPK + tid];
    }
    __syncthreads();
    int c0 = tid * 8;
    float4 a0 = {0, 0, 0, 0}, a1 = {0, 0, 0, 0};
    for (int v = 0; v < TOPK; ++v) {
        float w = wvs[v];
        int id = wis[v];
        const float4* fr = (const float4*)&feats[(size_t)id * DF + c0];
        float4 g0 = fr[0], g1 = fr[1];
        a0.x += w * g0.x; a0.y += w * g0.y; a0.z += w * g0.z; a0.w += w * g0.w;
        a1.x += w * g1.x; a1.y += w * g1.y; a1.z += w * g1.z; a1.w += w * g1.w;
    }
    float4* op = (float4*)&out[(size_t)row * DF + c0];
    op[0] = a0;
    op[1] = a1;
}

extern "C" void kernel_launch(void* const* d_in, const int* in_sizes, int n_in,
                              void* d_out, int out_size, void* d_ws, size_t ws_size,
                              hipStream_t stream) {
    const float* feats = (const float*)d_in[0];
    const int* ei = (const int*)d_in[1];
    float* out = (float*)d_out;

    int* outcnt = (int*)d_ws;                     // 2048
    int* incur = outcnt + NN;                     // 2048 (in-degree after build)
    float* winv05 = (float*)(incur + NN);         // 2048
    int* gmaxq = (int*)(winv05 + NN);             // 64 (32 used; keeps T 8B-aligned)
    unsigned* T = (unsigned*)(gmaxq + 64);        // 12*2048*2 words (quad-packed CSC, pre-scaled)
    float* tkv = (float*)(T + MAXDQ * NN * 2);    // 2048*20
    int* tki = (int*)(tkv + NN * TOPK);           // 2048*20

    init_kernel<<<(MAXDQ * NN * 2 + 255) / 256, 256, 0, stream>>>(outcnt, incur, T);
    build_kernel<<<(NE + 255) / 256, 256, 0, stream>>>(ei, outcnt, incur, T);
    meta_kernel<<<1, 256, 0, stream>>>(outcnt, incur, winv05, gmaxq);
    push_topk_kernel<<<NN / NSRC, 512, 0, stream>>>(T, winv05, gmaxq, tkv, tki);
    final_kernel<<<NN, 256, 0, stream>>>(feats, tkv, tki, out);
}

// Round 7
// 548.334 us; speedup vs baseline: 1.2691x; 1.2691x over previous
//
#include <hip/hip_runtime.h>

#define NN 2048
#define NE 32768
#define DF 2048
#define TOPK 20
#define RMAXF 1e-5f
#define MAXD 48           // supported max in-degree (Poisson(16); verified by passing rounds)
#define MAXDQ (MAXD / 4)  // 12 quad-levels of 4 packed edges
#define SENTW 0x08000800u // two packed sentinel slot-ids (2048 -> PV[2048] == 0)
#define NSRC 4            // sources per block (float4-packed PV)
#define MAXROUNDS 64      // safety cap; provably unreachable (mass halves/round)
#define NL 4              // owned slots per thread (512 threads)

typedef __attribute__((ext_vector_type(4))) float f32x4;
typedef unsigned long long u64;

// ---------------- init: zero counters, sentinel-fill transposed in-edge table ----------------
__global__ __launch_bounds__(256) void init_kernel(int* __restrict__ outcnt, int* __restrict__ indeg,
                                                   unsigned* __restrict__ T) {
    int i = blockIdx.x * 256 + threadIdx.x;
    if (i < MAXDQ * NN * 2) T[i] = SENTW;
    if (i < NN) { outcnt[i] = 0; indeg[i] = 0; }
}

// ---------------- count: out-degree and in-degree ----------------
__global__ __launch_bounds__(256) void count_kernel(const int* __restrict__ ei, int* __restrict__ outcnt,
                                                    int* __restrict__ indeg) {
    int e = blockIdx.x * 256 + threadIdx.x;
    if (e >= NE) return;
    atomicAdd(&outcnt[ei[e]], 1);
    atomicAdd(&indeg[ei[NE + e]], 1);
}

// ---------------- meta: degree-sorted slot permutation + slot-indexed weights/bounds ----------------
// Counting sort by in-degree: each wave of the push kernel then owns 64 slots of near-equal
// in-degree, so the wave-uniform gather bound (per-64-slot max) drops from ~27 (random
// grouping, Poisson(16)) to ~local mean -> ~40% fewer gather slots. Order within equal
// degree is arbitrary (top-k tie-break uses original ids via u64 keys).
__global__ __launch_bounds__(256) void meta_kernel(const int* __restrict__ outcnt, const int* __restrict__ indeg,
                                                   int* __restrict__ perm, int* __restrict__ invperm,
                                                   float* __restrict__ wvslot, int* __restrict__ gmaxq,
                                                   int* __restrict__ cursor) {
    __shared__ int hist[MAXD + 2];
    __shared__ int start[MAXD + 2];
    int tid = threadIdx.x;
    if (tid < MAXD + 2) hist[tid] = 0;
    __syncthreads();
#pragma unroll
    for (int l = 0; l < 8; ++l) {
        int j = tid + (l << 8);
        atomicAdd(&hist[min(indeg[j], MAXD)], 1);
        cursor[j] = 0;
    }
    __syncthreads();
    if (tid == 0) {
        int s = 0;
        for (int k = 0; k <= MAXD; ++k) { start[k] = s; s += hist[k]; }
    }
    __syncthreads();
#pragma unroll
    for (int l = 0; l < 8; ++l) {
        int j = tid + (l << 8);
        int t = atomicAdd(&start[min(indeg[j], MAXD)], 1);
        perm[t] = j;
        invperm[j] = t;
    }
    __threadfence();
    __syncthreads();  // perm[] fully written & visible before cross-thread reads below
#pragma unroll
    for (int l = 0; l < 8; ++l) {
        int t = tid + (l << 8);
        int c = outcnt[perm[t]];
        wvslot[t] = c ? 0.5f / (float)c : 0.0f;  // deg==0 row spreads nothing
    }
    if (tid < 32) {
        int m = 0;
        for (int k = 0; k < 64; ++k) m = max(m, indeg[perm[tid * 64 + k]]);
        m = min(m, MAXD);
        gmaxq[tid] = (m + 3) >> 2;
    }
}

// ---------------- fill: transposed (CSC) quad-packed table in SLOT coordinates ----------------
// Quad-level q of dest-slot sd at uint2 index q*NN + sd; halfwords hold source SLOT ids.
// Slot p: word = (p>>2)*(NN*2) + sd*2 + ((p>>1)&1), halfword = p&1. And+Or race only with
// the other half of the same word (disjoint masks) -> safe.
__global__ __launch_bounds__(256) void fill_kernel(const int* __restrict__ ei, const int* __restrict__ invperm,
                                                   int* __restrict__ cursor, unsigned* __restrict__ T) {
    int e = blockIdx.x * 256 + threadIdx.x;
    if (e >= NE) return;
    int s = ei[e];
    int d = ei[NE + e];
    int p = atomicAdd(&cursor[d], 1);
    if (p < MAXD) {
        int sd = invperm[d];
        int wi = (p >> 2) * (NN * 2) + sd * 2 + ((p >> 1) & 1);
        int sh = (p & 1) * 16;
        atomicAnd(&T[wi], ~(0xFFFFu << sh));
        atomicOr(&T[wi], ((unsigned)invperm[s]) << sh);
    }
}

// ---------------- 4-source local push (gather form, ping-pong PV) + key-based top-20 ----------------
// Inner gather loop kept VERBATIM from the proven round-5 codegen (116 VGPR, reads in
// flight); round 6's "optimized" variant collapsed to 52 VGPR serialized reads and
// regressed 21%. All state is slot-indexed; sorted slots cut gather quads ~40%.
__global__ __launch_bounds__(512, 2) void push_topk_kernel(const unsigned* __restrict__ Tw,
                                                           const float* __restrict__ wvslotg,
                                                           const int* __restrict__ gmaxqg,
                                                           const int* __restrict__ permg,
                                                           const int* __restrict__ invpermg,
                                                           float* __restrict__ tkv, int* __restrict__ tki) {
    __shared__ f32x4 PVbuf[2 * (NN + 1)];  // [parity][slot]; [*][NN] = zero sentinel
    __shared__ int swf[2][8];              // [parity][wave] convergence flags

    const int tid = threadIdx.x;
    const int lane = tid & 63;
    const int wvid = tid >> 6;  // 0..7
    const int s0 = blockIdx.x * NSRC;
    const uint2* Tq = (const uint2*)Tw;
    const f32x4 z = {0.f, 0.f, 0.f, 0.f};

    f32x4 Rr[NL], Pr[NL];
    float wvv[NL];
    int gql[NL];  // wave-uniform in-degree bounds -> SGPRs (group of j=tid+l*512 is wvid+8l)
#pragma unroll
    for (int l = 0; l < NL; ++l) gql[l] = __builtin_amdgcn_readfirstlane(gmaxqg[wvid + (l << 3)]);

#pragma unroll
    for (int l = 0; l < NL; ++l) {
        int j = tid + (l << 9);
        Rr[l] = z;
        Pr[l] = z;
        wvv[l] = wvslotg[j];
        PVbuf[j] = z;  // buffer 0; buffer 1 fully written in round 0 before round 1 reads it
    }
    if (tid == 0) { PVbuf[NN] = z; PVbuf[2 * NN + 1] = z; }  // both sentinels, never rewritten
    // fold reference round 1 (only the source is >= RMAX): P[s][c]=0.5, PV0[slot(s)][c]=winv05[s]
    int srcslot[NSRC];
#pragma unroll
    for (int c = 0; c < NSRC; ++c) srcslot[c] = invpermg[s0 + c];
#pragma unroll
    for (int l = 0; l < NL; ++l) {
        int j = tid + (l << 9);
#pragma unroll
        for (int c = 0; c < NSRC; ++c) {
            if (j == srcslot[c]) {
                Pr[l][c] = 0.5f;
                ((float*)&PVbuf[j])[c] = wvv[l];  // compile-time c -> single ds_write_b32
            }
        }
    }
    __syncthreads();

    int flagreg = 1;
    for (int round = 0; flagreg && round < MAXROUNDS; ++round) {
        const int p = round & 1;
        const f32x4* PVc = PVbuf + p * (NN + 1);  // read buffer
        f32x4* PVn = PVbuf + (p ^ 1) * (NN + 1);  // write buffer
        bool above = false;
#pragma unroll
        for (int l = 0; l < NL; ++l) {
            int j = tid + (l << 9);
            const uint2* colq = Tq + j;
            int gq = gql[l];
            f32x4 d = z;
#pragma unroll 2
            for (int q = 0; q < gq; ++q) {
                uint2 w = colq[q * NN];  // coalesced 512B/wave, L2-resident
                d += PVc[w.x & 0xFFFFu];
                d += PVc[w.x >> 16];
                d += PVc[w.y & 0xFFFFu];
                d += PVc[w.y >> 16];
            }
            f32x4 rn = Rr[l] + d;
            f32x4 pv;
#pragma unroll
            for (int u = 0; u < 4; ++u) {
                float r = rn[u];
                if (r >= RMAXF) {
                    Pr[l][u] += 0.5f * r;
                    pv[u] = r * wvv[l];
                    rn[u] = 0.0f;
                    above = true;
                } else {
                    pv[u] = 0.0f;
                }
            }
            PVn[j] = pv;
            Rr[l] = rn;
        }
        int anyv = __any(above) ? 1 : 0;     // all lanes participate
        if (lane == 0) swf[p][wvid] = anyv;  // unconditional write -> no reset needed
        __syncthreads();                     // PVn writes + flags visible; PVc reads done
        flagreg = swf[p][0] | swf[p][1] | swf[p][2] | swf[p][3] |
                  swf[p][4] | swf[p][5] | swf[p][6] | swf[p][7];
    }

    // ---- top-20 via u64 keys (permutation-invariant): key = (float_bits(P)<<32) | ~id ----
    // P >= 0 -> float-bit order == value order; ~id -> lowest original id on value ties
    // (matches stable lax.top_k). Keys live in the dead PV buffer (4 sources x 2048 x 8B).
    u64* K = (u64*)PVbuf;
#pragma unroll
    for (int l = 0; l < NL; ++l) {
        int j = tid + (l << 9);
        unsigned nid = ~(unsigned)permg[j];
#pragma unroll
        for (int c = 0; c < NSRC; ++c)
            K[c * NN + j] = ((u64)__float_as_uint(Pr[l][c]) << 32) | nid;
    }
    __syncthreads();

    const int w = wvid;  // wave id == source component; waves scan disjoint key arrays
    if (w < NSRC) {
        u64* Kw = K + w * NN;
        u64 bk = 0;
        int bs = 0;
#pragma unroll
        for (int k = 0; k < 32; ++k) {
            int n = lane + (k << 6);
            u64 kk = Kw[n];
            if (kk > bk) { bk = kk; bs = n; }
        }
        for (int s = 0; s < TOPK; ++s) {
            u64 mk = bk;
#pragma unroll
            for (int off = 32; off > 0; off >>= 1) {  // butterfly max (keys unique: ids distinct)
                u64 ok = __shfl_xor(mk, off, 64);
                if (ok > mk) mk = ok;
            }
            if (lane == 0) {
                tkv[(s0 + w) * TOPK + s] = __uint_as_float((unsigned)(mk >> 32));
                tki[(s0 + w) * TOPK + s] = (int)(~(unsigned)mk);
            }
            if (bk == mk) {  // unique owner pops winner, rescans its 32 slots
                Kw[bs] = 0;  // 0 < every real key (low word ~id >= ~2047 > 0)
                bk = 0;
                bs = 0;
#pragma unroll
                for (int k = 0; k < 32; ++k) {
                    int n = lane + (k << 6);
                    u64 kk = Kw[n];
                    if (kk > bk) { bk = kk; bs = n; }
                }
            }
        }
    }
}

// ---------------- out[row] = sum_v w_v * feats[idx_v] ----------------
__global__ __launch_bounds__(256) void final_kernel(const float* __restrict__ feats, const float* __restrict__ tkv,
                                                    const int* __restrict__ tki, float* __restrict__ out) {
    __shared__ float wvs[TOPK];
    __shared__ int wis[TOPK];
    int row = blockIdx.x, tid = threadIdx.x;
    if (tid < TOPK) {
        wvs[tid] = tkv[row * TOPK + tid];
        wis[tid] = tki[row * TOPK + tid];
    }
    __syncthreads();
    int c0 = tid * 8;
    float4 a0 = {0, 0, 0, 0}, a1 = {0, 0, 0, 0};
    for (int v = 0; v < TOPK; ++v) {
        float w = wvs[v];
        int id = wis[v];
        const float4* fr = (const float4*)&feats[(size_t)id * DF + c0];
        float4 g0 = fr[0], g1 = fr[1];
        a0.x += w * g0.x; a0.y += w * g0.y; a0.z += w * g0.z; a0.w += w * g0.w;
        a1.x += w * g1.x; a1.y += w * g1.y; a1.z += w * g1.z; a1.w += w * g1.w;
    }
    float4* op = (float4*)&out[(size_t)row * DF + c0];
    op[0] = a0;
    op[1] = a1;
}

extern "C" void kernel_launch(void* const* d_in, const int* in_sizes, int n_in,
                              void* d_out, int out_size, void* d_ws, size_t ws_size,
                              hipStream_t stream) {
    const float* feats = (const float*)d_in[0];
    const int* ei = (const int*)d_in[1];
    float* out = (float*)d_out;

    int* outcnt = (int*)d_ws;                     // 2048
    int* indeg = outcnt + NN;                     // 2048
    int* cursor = indeg + NN;                     // 2048
    int* perm = cursor + NN;                      // 2048 (slot -> node id)
    int* invperm = perm + NN;                     // 2048 (node id -> slot)
    float* wvslot = (float*)(invperm + NN);       // 2048 (0.5/outdeg by slot)
    int* gmaxq = (int*)(wvslot + NN);             // 64 (32 used; keeps T 8B-aligned)
    unsigned* T = (unsigned*)(gmaxq + 64);        // 12*2048*2 words (quad-packed CSC, slot ids)
    float* tkv = (float*)(T + MAXDQ * NN * 2);    // 2048*20
    int* tki = (int*)(tkv + NN * TOPK);           // 2048*20

    init_kernel<<<(MAXDQ * NN * 2 + 255) / 256, 256, 0, stream>>>(outcnt, indeg, T);
    count_kernel<<<(NE + 255) / 256, 256, 0, stream>>>(ei, outcnt, indeg);
    meta_kernel<<<1, 256, 0, stream>>>(outcnt, indeg, perm, invperm, wvslot, gmaxq, cursor);
    fill_kernel<<<(NE + 255) / 256, 256, 0, stream>>>(ei, invperm, cursor, T);
    push_topk_kernel<<<NN / NSRC, 512, 0, stream>>>(T, wvslot, gmaxq, perm, invperm, tkv, tki);
    final_kernel<<<NN, 256, 0, stream>>>(feats, tkv, tki, out);
}